// Round 18
// baseline (851.900 us; speedup 1.0000x reference)
//
#include <hip/hip_runtime.h>
#include <math.h>

// ---------------------------------------------------------------------------
// Types / helpers
// ---------------------------------------------------------------------------
using u16 = unsigned short;
typedef __attribute__((ext_vector_type(8))) short short8;   // 8 x bf16 (raw bits)
typedef __attribute__((ext_vector_type(4))) float f32x4;
typedef __attribute__((ext_vector_type(16))) float f32x16;
typedef __attribute__((ext_vector_type(4))) u16 u16x4;

#define DEV __device__ __forceinline__

DEV u16 f2bf(float f) {                       // f32 -> bf16, round-nearest-even
    unsigned u = __float_as_uint(f);
    u += 0x7fffu + ((u >> 16) & 1u);
    return (u16)(u >> 16);
}
DEV float bf2f(u16 h) { return __uint_as_float(((unsigned)h) << 16); }

DEV short8 ld16(const u16* p) { return *reinterpret_cast<const short8*>(p); }

DEV float gelu_f(float x) {                   // tanh-approx gelu, exp2-based
    const float u = x * (0.7978845608f + 0.0356774081f * x * x);
    const float e = __builtin_amdgcn_exp2f(u * 2.885390082f);   // e^(2u)
    const float t = 1.f - 2.f * __builtin_amdgcn_rcpf(e + 1.f); // tanh(u)
    return 0.5f * x * (1.f + t);
}

DEV unsigned pk2(float a, float b) {          // packed bf16x2 via HW cvt (RNE)
    unsigned r;
    asm("v_cvt_pk_bf16_f32 %0, %1, %2" : "=v"(r) : "v"(a), "v"(b));
    return r;
}

// async global->LDS, 16B per lane, LDS dest = wave-uniform base + lane*16
#define GLL16(gp, lp)                                                          \
    __builtin_amdgcn_global_load_lds(                                          \
        (const __attribute__((address_space(1))) void*)(gp),                   \
        (__attribute__((address_space(3))) void*)(lp), 16, 0, 0)

#define VMC(n) asm volatile("s_waitcnt vmcnt(" #n ")" ::: "memory")
#define LGKM0() asm volatile("s_waitcnt lgkmcnt(0)" ::: "memory")

// ---------------------------------------------------------------------------
// fp32 -> bf16 convert, all four weights in one grid-stride dispatch
// ---------------------------------------------------------------------------
__global__ __launch_bounds__(256) void cvt_all(
    const float* __restrict__ s0, const float* __restrict__ s1,
    const float* __restrict__ s2, const float* __restrict__ s3,
    u16* __restrict__ d0, u16* __restrict__ d1,
    u16* __restrict__ d2, u16* __restrict__ d3) {
    for (long i = (long)blockIdx.x * 256 + threadIdx.x; i < 3145728;
         i += (long)gridDim.x * 256) {
        const float* s; u16* d; long j = i;
        if (j < 786432)       { s = s0; d = d0; }
        else if (j < 1048576) { s = s1; d = d1; j -= 786432; }
        else if (j < 2097152) { s = s2; d = d2; j -= 1048576; }
        else                  { s = s3; d = d3; j -= 2097152; }
        float4 v = reinterpret_cast<const float4*>(s)[j];
        u16x4 o;
        o.x = f2bf(v.x); o.y = f2bf(v.y); o.z = f2bf(v.z); o.w = f2bf(v.w);
        reinterpret_cast<u16x4*>(d)[j] = o;
    }
}

// ---------------------------------------------------------------------------
// LayerNorm (fp32 in) -> bf16 out.  One block per row, 256 threads x 4 floats.
// ---------------------------------------------------------------------------
__global__ __launch_bounds__(256) void ln_bf16(const float* __restrict__ x,
                                               const float* __restrict__ gm,
                                               const float* __restrict__ bt,
                                               u16* __restrict__ out) {
    const int row = blockIdx.x, tid = threadIdx.x;
    const float4 v = reinterpret_cast<const float4*>(x + (long)row * 1024)[tid];
    float s  = v.x + v.y + v.z + v.w;
    float sq = v.x * v.x + v.y * v.y + v.z * v.z + v.w * v.w;
#pragma unroll
    for (int off = 1; off <= 32; off <<= 1) {
        s  += __shfl_xor(s, off);
        sq += __shfl_xor(sq, off);
    }
    __shared__ float ss[4], ssq[4];
    const int wave = tid >> 6, lane = tid & 63;
    if (lane == 0) { ss[wave] = s; ssq[wave] = sq; }
    __syncthreads();
    s  = ss[0] + ss[1] + ss[2] + ss[3];
    sq = ssq[0] + ssq[1] + ssq[2] + ssq[3];
    const float mu   = s * (1.f / 1024.f);
    const float var  = sq * (1.f / 1024.f) - mu * mu;
    const float rstd = rsqrtf(var + 1e-5f);
    const float4 g4 = reinterpret_cast<const float4*>(gm)[tid];
    const float4 b4 = reinterpret_cast<const float4*>(bt)[tid];
    u16x4 o;
    o.x = f2bf((v.x - mu) * rstd * g4.x + b4.x);
    o.y = f2bf((v.y - mu) * rstd * g4.y + b4.y);
    o.z = f2bf((v.z - mu) * rstd * g4.z + b4.z);
    o.w = f2bf((v.w - mu) * rstd * g4.w + b4.w);
    reinterpret_cast<u16x4*>(out + (long)row * 1024)[tid] = o;
}

// ---------------------------------------------------------------------------
// FC1 GEMM: 512 threads, 8 waves (2M x 4N), 128x256 tile, BK=32 depth-2
// counted-vmcnt pipeline, 48 KB LDS -> 3 blocks/CU = 24 waves/CU.
// Per-wave work identical to the 4-wave kernel (64x64, 16 MFMA/iter).
// Staging: 3 gload_lds per thread per tile (A:1, B:2) -> steady VMC(3).
// 8x4 supertile of 128x256 tiles; gelu epilogue, direct u16x4 stores.
// ---------------------------------------------------------------------------
__global__ __launch_bounds__(512, 6) void gemm_fc1(
    const u16* __restrict__ A, const u16* __restrict__ B,
    const float* __restrict__ bias, u16* __restrict__ outb,
    int M, int N, int K, int ldk) {
    __shared__ u16 shpool[24576];   // 2 bufs x (A 4096 + B 8192) u16

    const int tid = threadIdx.x;
    const int w = tid >> 6, lane = tid & 63;
    const int lo = lane & 15, g = lane >> 4;
    const int wr = w >> 2, wc = w & 3;

    // XCD-chunked wgid; 8x4 supertile of 128x256 tiles
    const int nwg = gridDim.x, chunk = nwg >> 3;
    const int wgid = (blockIdx.x & 7) * chunk + (blockIdx.x >> 3);
    const int nSmCol = N >> 10;                  // (N/256)/4 supertile cols
    const int s = wgid >> 5, w5 = wgid & 31;
    const int bm = (s / nSmCol) * 8 + (w5 >> 2);
    const int bn = (s % nSmCol) * 4 + (w5 & 3);
    const int row0 = bm * 128, col0 = bn * 256;

    // staging source (pre-swizzled logical chunk so linear LDS dest = swizzled)
    const int lrow = lane >> 2;
    const int lg   = (lane & 3) ^ ((lane >> 3) & 3);
    const u16* Ag = A + (long)(row0 + w * 16 + lrow) * ldk + lg * 8;
    const u16* Bg = B + (long)(col0 + w * 32 + lrow) * ldk + lg * 8;

    auto STAGE = [&](int tb, int kt) {
        u16* Al = shpool + tb * 12288 + w * 512;
        u16* Bl = shpool + tb * 12288 + 4096 + w * 1024;
        GLL16(Ag + (long)kt * 32, Al);
        GLL16(Bg + (long)kt * 32, Bl);
        GLL16(Bg + 16 * (long)ldk + (long)kt * 32, Bl + 512);
    };

    const int agp = g ^ ((lo >> 1) & 3);      // swizzled ds_read chunk
    f32x4 acc[4][4] = {};

    STAGE(0, 0);
    STAGE(1, 1);

    const int T = K >> 5;
    for (int t = 0; t < T; ++t) {
        const int cur = t & 1;
        if (t + 1 < T) { VMC(3); } else { VMC(0); }
        __builtin_amdgcn_s_barrier();         // tile t visible to all waves
        const u16* As = shpool + cur * 12288;
        const u16* Bs = As + 4096;
        short8 af[4], bfr[4];
#pragma unroll
        for (int m = 0; m < 4; ++m)
            af[m] = ld16(&As[(wr * 64 + m * 16 + lo) * 32 + agp * 8]);
#pragma unroll
        for (int n = 0; n < 4; ++n)
            bfr[n] = ld16(&Bs[(wc * 64 + n * 16 + lo) * 32 + agp * 8]);
        LGKM0();                              // own reads drained (WAR fence)
        __builtin_amdgcn_s_barrier();         // all waves' reads done
        if (t + 2 < T) STAGE(cur, t + 2);     // safe overwrite; flies under MFMA
#pragma unroll
        for (int m = 0; m < 4; ++m)
#pragma unroll
            for (int n = 0; n < 4; ++n)
                acc[m][n] = __builtin_amdgcn_mfma_f32_16x16x32_bf16(
                    bfr[n], af[m], acc[m][n], 0, 0, 0);
    }

    // gelu epilogue, direct u16x4 stores
#pragma unroll
    for (int n = 0; n < 4; ++n) {
        const int cb = col0 + wc * 64 + n * 16 + g * 4;
        const float4 b4 = *reinterpret_cast<const float4*>(&bias[cb]);
#pragma unroll
        for (int m = 0; m < 4; ++m) {
            const int r = row0 + wr * 64 + m * 16 + lo;
            u16x4 o = {f2bf(gelu_f(acc[m][n][0] + b4.x)),
                       f2bf(gelu_f(acc[m][n][1] + b4.y)),
                       f2bf(gelu_f(acc[m][n][2] + b4.z)),
                       f2bf(gelu_f(acc[m][n][3] + b4.w))};
            *reinterpret_cast<u16x4*>(&outb[(long)r * N + cb]) = o;
        }
    }
}

// ---------------------------------------------------------------------------
// GEMM, templated BK (4-wave 128x128; R17-verified).
//   BK=32: depth-2, 32 KB LDS, 4 blocks/CU.   BK=64: depth-2, 64 KB, 2/CU.
// EPI: 2 = fp32 out + residual, 3 = QKV (Q pre-scaled; Q/K restaged; V -> Vt).
// ---------------------------------------------------------------------------
#define TS(c, r) ((c) * 128 + (((((r) >> 3) ^ ((c) & 15))) << 3) + ((r) & 7))
#define CS(r, ck) ((r) * 128 + ((((ck) ^ ((r) & 15))) << 3))

template <int EPI, int BK>
__global__ __launch_bounds__(256, (BK == 32) ? 4 : 2) void gemm_bt(
    const u16* __restrict__ A, const u16* __restrict__ B,
    const float* __restrict__ bias, const float* res, float* outf,
    u16* __restrict__ outb, u16* __restrict__ Qb, u16* __restrict__ Kb,
    u16* __restrict__ Vtb, int M, int N, int K, int ldk) {
    constexpr int BUFU = (BK == 32) ? 8192 : 16384;   // u16 per buffer
    __shared__ u16 shpool[2 * BUFU];

    const int tid = threadIdx.x;
    const int wave = tid >> 6, lane = tid & 63;
    const int lo = lane & 15, g = lane >> 4;
    const int wr = wave >> 1, wc = wave & 1;

    const int nwg = gridDim.x, chunk = nwg >> 3;
    const int wgid = (blockIdx.x & 7) * chunk + (blockIdx.x >> 3);
    const int nSmCol = N >> 10;                  // (N/128)/8 supertile cols
    const int s = wgid >> 6, w6 = wgid & 63;
    const int bm = (s / nSmCol) * 8 + (w6 >> 3);
    const int bn = (s % nSmCol) * 8 + (w6 & 7);
    const int row0 = bm * 128, col0 = bn * 128;

    const u16 *Ag, *Bg;
    if constexpr (BK == 32) {
        const int lrow = lane >> 2;
        const int lg   = (lane & 3) ^ ((lane >> 3) & 3);
        Ag = A + (long)(row0 + wave * 16 + lrow) * ldk + lg * 8;
        Bg = B + (long)(col0 + wave * 16 + lrow) * ldk + lg * 8;
    } else {
        const int lg = (lane & 7) ^ ((lane >> 3) & 7);
        Ag = A + (long)(row0 + wave * 32 + (lane >> 3)) * ldk + lg * 8;
        Bg = B + (long)(col0 + wave * 32 + (lane >> 3)) * ldk + lg * 8;
    }

    auto STAGE = [&](int tb, int kt) {
        if constexpr (BK == 32) {
            u16* Al = shpool + tb * 8192 + wave * 512;
            u16* Bl = Al + 4096;
            GLL16(Ag + (long)kt * 32, Al);
            GLL16(Ag + 64 * (long)ldk + (long)kt * 32, Al + 2048);
            GLL16(Bg + (long)kt * 32, Bl);
            GLL16(Bg + 64 * (long)ldk + (long)kt * 32, Bl + 2048);
        } else {
            u16* Al = shpool + tb * 16384 + wave * 2048;
            u16* Bl = Al + 8192;
            GLL16(Ag + (long)kt * 64,                  Al);
            GLL16(Ag + (long)kt * 64 +  8 * (long)ldk, Al + 512);
            GLL16(Ag + (long)kt * 64 + 16 * (long)ldk, Al + 1024);
            GLL16(Ag + (long)kt * 64 + 24 * (long)ldk, Al + 1536);
            GLL16(Bg + (long)kt * 64,                  Bl);
            GLL16(Bg + (long)kt * 64 +  8 * (long)ldk, Bl + 512);
            GLL16(Bg + (long)kt * 64 + 16 * (long)ldk, Bl + 1024);
            GLL16(Bg + (long)kt * 64 + 24 * (long)ldk, Bl + 1536);
        }
    };

    f32x4 acc[4][4] = {};

    STAGE(0, 0);
    STAGE(1, 1);

    const int T = K / BK;
    for (int t = 0; t < T; ++t) {
        const int cur = t & 1;
        if (t + 1 < T) {
            if constexpr (BK == 32) { VMC(4); } else { VMC(8); }
        } else { VMC(0); }
        __builtin_amdgcn_s_barrier();
        const u16* As = shpool + cur * BUFU;
        const u16* Bs = As + BUFU / 2;
        if constexpr (BK == 32) {
            short8 af[4], bfr[4];
            const int agp = g ^ ((lo >> 1) & 3);
#pragma unroll
            for (int m = 0; m < 4; ++m)
                af[m] = ld16(&As[(wr * 64 + m * 16 + lo) * 32 + agp * 8]);
#pragma unroll
            for (int n = 0; n < 4; ++n)
                bfr[n] = ld16(&Bs[(wc * 64 + n * 16 + lo) * 32 + agp * 8]);
            LGKM0();
            __builtin_amdgcn_s_barrier();
            if (t + 2 < T) STAGE(cur, t + 2);
#pragma unroll
            for (int m = 0; m < 4; ++m)
#pragma unroll
                for (int n = 0; n < 4; ++n)
                    acc[m][n] = __builtin_amdgcn_mfma_f32_16x16x32_bf16(
                        bfr[n], af[m], acc[m][n], 0, 0, 0);
        } else {
            short8 af[2][4], bfr[2][4];
#pragma unroll
            for (int ks = 0; ks < 2; ++ks) {
                const int ch = ((ks * 4 + g) ^ (lo & 7)) * 8;
#pragma unroll
                for (int m = 0; m < 4; ++m)
                    af[ks][m] = ld16(&As[(wr * 64 + m * 16 + lo) * 64 + ch]);
#pragma unroll
                for (int n = 0; n < 4; ++n)
                    bfr[ks][n] = ld16(&Bs[(wc * 64 + n * 16 + lo) * 64 + ch]);
            }
            LGKM0();
            __builtin_amdgcn_s_barrier();
            if (t + 2 < T) STAGE(cur, t + 2);
#pragma unroll
            for (int ks = 0; ks < 2; ++ks)
#pragma unroll
                for (int m = 0; m < 4; ++m)
#pragma unroll
                    for (int n = 0; n < 4; ++n)
                        acc[m][n] = __builtin_amdgcn_mfma_f32_16x16x32_bf16(
                            bfr[ks][n], af[ks][m], acc[m][n], 0, 0, 0);
        }
    }

    // ---- EPI 3: QKV scatter (LDS reuse -> sync first) ----
    if constexpr (EPI == 3) {
        __syncthreads();
        const int part = col0 >> 10;          // 0=Q 1=K 2=V
        if (part == 2) {                      // V: transpose via LDS -> Vt
#pragma unroll
            for (int n = 0; n < 4; ++n) {
                const int cb = wc * 64 + n * 16 + g * 4;
                const float4 b4 = *reinterpret_cast<const float4*>(&bias[col0 + cb]);
#pragma unroll
                for (int m = 0; m < 4; ++m) {
                    const int rl = wr * 64 + m * 16 + lo;
                    shpool[TS(cb + 0, rl)] = f2bf(acc[m][n][0] + b4.x);
                    shpool[TS(cb + 1, rl)] = f2bf(acc[m][n][1] + b4.y);
                    shpool[TS(cb + 2, rl)] = f2bf(acc[m][n][2] + b4.z);
                    shpool[TS(cb + 3, rl)] = f2bf(acc[m][n][3] + b4.w);
                }
            }
            __syncthreads();
            const int c = tid >> 1, hlf = tid & 1;
            const int dcol = (col0 - 2048) + c;
            const int head = dcol >> 6, d = dcol & 63;
            const int bb = row0 >> 11;
            u16* dst = Vtb + ((long)(bb * 16 + head) * 64 + d) * 2048 +
                       (row0 & 2047) + hlf * 64;
            const u16* srcb = shpool + c * 128;
#pragma unroll
            for (int i = 0; i < 8; ++i) {
                const int pc = (hlf * 8 + i) ^ (c & 15);
                *reinterpret_cast<short8*>(dst + i * 8) =
                    *reinterpret_cast<const short8*>(srcb + pc * 8);
            }
            return;
        }
        const float qs = (part == 0) ? 0.18033688f : 1.0f;  // Q in log2 domain
#pragma unroll
        for (int n = 0; n < 4; ++n) {
            const int cb = col0 + wc * 64 + n * 16 + g * 4;
            const float4 b4 = *reinterpret_cast<const float4*>(&bias[cb]);
            const int ch = wc * 8 + n * 2 + (g >> 1);
#pragma unroll
            for (int m = 0; m < 4; ++m) {
                const int r = wr * 64 + m * 16 + lo;
                u16x4 o = {f2bf((acc[m][n][0] + b4.x) * qs),
                           f2bf((acc[m][n][1] + b4.y) * qs),
                           f2bf((acc[m][n][2] + b4.z) * qs),
                           f2bf((acc[m][n][3] + b4.w) * qs)};
                *reinterpret_cast<u16x4*>(&shpool[CS(r, ch) + (g & 1) * 4]) = o;
            }
        }
        __syncthreads();
        const int row = tid >> 1, hl = tid & 1;
        const int headbase = (col0 & 1023) >> 6;
        const int head = headbase + hl;
        const int bb = row0 >> 11;
        const int srow = (row0 & 2047) + row;
        u16* drow = (part == 0 ? Qb : Kb) +
                    ((long)(bb * 16 + head) * 2048 + srow) * 64;
        const int rk = row & 15;
#pragma unroll
        for (int i = 0; i < 8; ++i) {
            const int ck = hl * 8 + i;
            *reinterpret_cast<short8*>(drow + i * 8) =
                *reinterpret_cast<const short8*>(&shpool[row * 128 + ((ck ^ rk) << 3)]);
        }
        return;
    }

    // ---- EPI 2: fp32 out + residual (direct) ----
#pragma unroll
    for (int n = 0; n < 4; ++n) {
        const int cb = col0 + wc * 64 + n * 16 + g * 4;
        const float4 b4 = *reinterpret_cast<const float4*>(&bias[cb]);
#pragma unroll
        for (int m = 0; m < 4; ++m) {
            const int r = row0 + wr * 64 + m * 16 + lo;
            const float4 rr = *reinterpret_cast<const float4*>(&res[(long)r * N + cb]);
            float4 o = {rr.x + acc[m][n][0] + b4.x, rr.y + acc[m][n][1] + b4.y,
                        rr.z + acc[m][n][2] + b4.z, rr.w + acc[m][n][3] + b4.w};
            *reinterpret_cast<float4*>(&outf[(long)r * N + cb]) = o;
        }
    }
}

// ---------------------------------------------------------------------------
// Causal flash attention, 32x32x16 MFMA, LDS-staged K/V (counted-vmcnt
// double-buffer).  Block = 4 waves = one (bh, 128-row q-strip).
// ---------------------------------------------------------------------------
__global__ __launch_bounds__(256) void attn_fwd32(
    const u16* __restrict__ Q, const u16* __restrict__ K,
    const u16* __restrict__ Vt, u16* __restrict__ O) {
    __shared__ u16 kvl[2][8192];   // per buf: K tile 4096 u16, V tile 4096 u16
    const int bh = blockIdx.x;
    const int strip = 15 - blockIdx.y;       // heavy strips dispatch first
    const int wave = threadIdx.x >> 6, lane = threadIdx.x & 63;
    const int lq = lane & 31, hi = lane >> 5;
    const int qw = strip * 128 + wave * 32;

    const u16* Kg = K + (long)bh * 2048 * 64;
    const u16* Vg = Vt + (long)bh * 64 * 2048;
    const int bb = bh >> 4, h = bh & 15;
    const u16* Qp = Q + ((long)bh * 2048 + qw) * 64;

    const int srow = wave * 8 + (lane >> 3);         // 0..31
    const int sc   = (lane & 7) ^ (srow & 7);        // logical 16B chunk

#define ASTAGE(b, kt) do {                                                     \
        const long kvb = (long)(kt) * 64;                                      \
        GLL16(Kg + (kvb + srow) * 64 + sc * 8,        &kvl[b][wave * 512]);    \
        GLL16(Kg + (kvb + 32 + srow) * 64 + sc * 8,   &kvl[b][2048 + wave * 512]); \
        GLL16(Vg + (long)srow * 2048 + kvb + sc * 8,  &kvl[b][4096 + wave * 512]); \
        GLL16(Vg + (long)(32 + srow) * 2048 + kvb + sc * 8,                    \
              &kvl[b][6144 + wave * 512]);                                     \
    } while (0)

    short8 qf[4];
#pragma unroll
    for (int ks = 0; ks < 4; ++ks)
        qf[ks] = ld16(Qp + lq * 64 + ks * 16 + hi * 8);

    f32x16 o0 = {}, o1 = {};
    float m = -1e30f, l = 0.f;
    const int q_abs = qw + lq;
    const int my_end = qw + 32;              // wave's causal kv end
    const int T = 2 * (strip + 1);           // block kv tiles (>= 2)
    const int swp = lq & 7;                  // read-side swizzle key

    ASTAGE(0, 0);
    ASTAGE(1, 1);

    for (int t = 0; t < T; ++t) {
        const int cur = t & 1;
        const int kv0 = t * 64;
        if (t + 1 < T) { VMC(4); } else { VMC(0); }
        __builtin_amdgcn_s_barrier();        // tile t landed for all waves
        const bool active = (kv0 < my_end);  // wave-uniform
        f32x16 s0 = {}, s1 = {};
        short8 vf0[4], vf1[4];
        if (active) {
            const u16* Kb = &kvl[cur][0];
            __builtin_amdgcn_s_setprio(1);
#pragma unroll
            for (int ks = 0; ks < 4; ++ks)
                s0 = __builtin_amdgcn_mfma_f32_32x32x16_bf16(
                    ld16(Kb + lq * 64 + ((ks * 2 + hi) ^ swp) * 8), qf[ks], s0, 0, 0, 0);
#pragma unroll
            for (int ks = 0; ks < 4; ++ks)
                s1 = __builtin_amdgcn_mfma_f32_32x32x16_bf16(
                    ld16(Kb + 2048 + lq * 64 + ((ks * 2 + hi) ^ swp) * 8), qf[ks], s1, 0, 0, 0);
            __builtin_amdgcn_s_setprio(0);
            const u16* Vb = &kvl[cur][4096];
#pragma unroll
            for (int c = 0; c < 4; ++c) {
                vf0[c] = ld16(Vb + lq * 64 + ((c * 2 + hi) ^ swp) * 8);
                vf1[c] = ld16(Vb + 2048 + lq * 64 + ((c * 2 + hi) ^ swp) * 8);
            }
        }
        LGKM0();                             // own LDS reads drained (WAR)
        __builtin_amdgcn_s_barrier();        // all waves' reads done
        if (t + 2 < T) ASTAGE(cur, t + 2);   // overwrite safe; flies under compute
        if (active) {
            float mt = -1e30f;
            if (kv0 + 64 >= my_end) {
#pragma unroll
                for (int r = 0; r < 16; ++r) {
                    const int kv = kv0 + (r & 3) + 8 * (r >> 2) + 4 * hi;
                    if (kv > q_abs) s0[r] = -1e30f;
                    mt = fmaxf(mt, s0[r]);
                    if (kv + 32 > q_abs) s1[r] = -1e30f;
                    mt = fmaxf(mt, s1[r]);
                }
            } else {
#pragma unroll
                for (int r = 0; r < 16; ++r)
                    mt = fmaxf(mt, fmaxf(s0[r], s1[r]));
            }
            mt = fmaxf(mt, __shfl_xor(mt, 32));

            if (!__all(mt <= m + 11.5f)) {
                const float mn = fmaxf(m, mt);
                const float corr = __builtin_amdgcn_exp2f(m - mn);
                m = mn;
                l *= corr;
                o0 *= corr; o1 *= corr;
            }
            float ps = 0.f;
#pragma unroll
            for (int r = 0; r < 16; ++r) {
                s0[r] = __builtin_amdgcn_exp2f(s0[r] - m); ps += s0[r];
                s1[r] = __builtin_amdgcn_exp2f(s1[r] - m); ps += s1[r];
            }
            l += ps;

            short8 pf[4];
#pragma unroll
            for (int c = 0; c < 4; ++c) {
                const f32x16& src = (c >> 1) ? s1 : s0;
                const int b = (c & 1) * 8;
                const unsigned A0 = pk2(src[b + 0], src[b + 1]);
                const unsigned A1 = pk2(src[b + 2], src[b + 3]);
                const unsigned B0 = pk2(src[b + 4], src[b + 5]);
                const unsigned B1 = pk2(src[b + 6], src[b + 7]);
                const unsigned S0 = hi ? A0 : B0;
                const unsigned S1 = hi ? A1 : B1;
                const unsigned R0 = (unsigned)__shfl_xor((int)S0, 32);
                const unsigned R1 = (unsigned)__shfl_xor((int)S1, 32);
                union { unsigned u[4]; short8 v; } fr;
                fr.u[0] = hi ? R0 : A0;
                fr.u[1] = hi ? R1 : A1;
                fr.u[2] = hi ? B0 : R0;
                fr.u[3] = hi ? B1 : R1;
                pf[c] = fr.v;
            }

            __builtin_amdgcn_s_setprio(1);
#pragma unroll
            for (int c = 0; c < 4; ++c) {
                o0 = __builtin_amdgcn_mfma_f32_32x32x16_bf16(
                    vf0[c], pf[c], o0, 0, 0, 0);
                o1 = __builtin_amdgcn_mfma_f32_32x32x16_bf16(
                    vf1[c], pf[c], o1, 0, 0, 0);
            }
            __builtin_amdgcn_s_setprio(0);
        }
    }
#undef ASTAGE

    l += __shfl_xor(l, 32);
    const float inv = 1.f / l;
    u16* Orow = O + ((long)(bb * 2048 + qw + lq)) * 1024 + h * 64;
#pragma unroll
    for (int k4 = 0; k4 < 4; ++k4) {
        u16x4 w0, w1;
#pragma unroll
        for (int j = 0; j < 4; ++j) {
            w0[j] = f2bf(o0[k4 * 4 + j] * inv);
            w1[j] = f2bf(o1[k4 * 4 + j] * inv);
        }
        *reinterpret_cast<u16x4*>(Orow + 8 * k4 + 4 * hi)      = w0;
        *reinterpret_cast<u16x4*>(Orow + 32 + 8 * k4 + 4 * hi) = w1;
    }
}

// ---------------------------------------------------------------------------
// launch
// ---------------------------------------------------------------------------
extern "C" void kernel_launch(void* const* d_in, const int* in_sizes, int n_in,
                              void* d_out, int out_size, void* d_ws, size_t ws_size,
                              hipStream_t stream) {
    const float* x      = (const float*)d_in[0];
    const float* ln1_g  = (const float*)d_in[1];
    const float* ln1_b  = (const float*)d_in[2];
    const float* qkv_w  = (const float*)d_in[3];
    const float* qkv_b  = (const float*)d_in[4];
    const float* out_w  = (const float*)d_in[5];
    const float* out_b  = (const float*)d_in[6];
    const float* ln2_g  = (const float*)d_in[7];
    const float* ln2_b  = (const float*)d_in[8];
    const float* fc1_w  = (const float*)d_in[9];
    const float* fc1_b  = (const float*)d_in[10];
    const float* fc2_w  = (const float*)d_in[11];
    const float* fc2_b  = (const float*)d_in[12];
    float* out = (float*)d_out;

    const size_t MB = 1024ull * 1024ull;
    if (ws_size < 120 * MB) return;
    char* ws = (char*)d_ws;
    u16* wqkv = (u16*)(ws + 0);        // 6 MB
    u16* wout = (u16*)(ws + 6 * MB);   // 2 MB
    u16* wfc1 = (u16*)(ws + 8 * MB);   // 8 MB
    u16* wfc2 = (u16*)(ws + 16 * MB);  // 8 MB
    u16* hbuf = (u16*)(ws + 24 * MB);  // 16 MB  (LN output, bf16)
    u16* obuf = (u16*)(ws + 40 * MB);  // 16 MB  (attn output, bf16)
    u16* Qb   = (u16*)(ws + 56 * MB);  // 16 MB
    u16* Kb   = (u16*)(ws + 72 * MB);  // 16 MB
    u16* Vtb  = (u16*)(ws + 88 * MB);  // 16 MB
    u16* gbuf = (u16*)(ws + 56 * MB);  // 64 MB  (FFN hidden, reuses Q/K/Vt)

    cvt_all<<<dim3(2048), 256, 0, stream>>>(qkv_w, out_w, fc1_w, fc2_w,
                                            wqkv, wout, wfc1, wfc2);

    ln_bf16<<<8192, 256, 0, stream>>>(x, ln1_g, ln1_b, hbuf);
    // QKV: BK32 depth-2, 4 blocks/CU, 1536 blocks
    gemm_bt<3, 32><<<dim3(1536), 256, 0, stream>>>(hbuf, wqkv, qkv_b, nullptr,
                                                   nullptr, nullptr, Qb, Kb, Vtb,
                                                   8192, 3072, 1024, 1024);
    attn_fwd32<<<dim3(64, 16), 256, 0, stream>>>(Qb, Kb, Vtb, obuf);
    // out-proj: grid-capped (512 blocks) -> BK64
    gemm_bt<2, 64><<<dim3(512), 256, 0, stream>>>(obuf, wout, out_b, x, out,
                                                  nullptr, nullptr, nullptr, nullptr,
                                                  8192, 1024, 1024, 1024);
    ln_bf16<<<8192, 256, 0, stream>>>(out, ln2_g, ln2_b, hbuf);
    // FC1: 512-thread 128x256 kernel, 3 blocks/CU, 1024 blocks
    gemm_fc1<<<dim3(1024), 512, 0, stream>>>(hbuf, wfc1, fc1_b, gbuf,
                                             8192, 4096, 1024, 1024);
    // FC2: grid-capped (512 blocks), K=4096 -> BK64
    gemm_bt<2, 64><<<dim3(512), 256, 0, stream>>>(gbuf, wfc2, fc2_b, out, out,
                                                  nullptr, nullptr, nullptr, nullptr,
                                                  8192, 1024, 4096, 4096);
}

// Round 19
// 363.303 us; speedup vs baseline: 2.3449x; 2.3449x over previous
//
#include <hip/hip_runtime.h>
#include <math.h>

// ---------------------------------------------------------------------------
// Types / helpers
// ---------------------------------------------------------------------------
using u16 = unsigned short;
typedef __attribute__((ext_vector_type(8))) short short8;   // 8 x bf16 (raw bits)
typedef __attribute__((ext_vector_type(4))) float f32x4;
typedef __attribute__((ext_vector_type(16))) float f32x16;
typedef __attribute__((ext_vector_type(4))) u16 u16x4;

#define DEV __device__ __forceinline__

DEV u16 f2bf(float f) {                       // f32 -> bf16, round-nearest-even
    unsigned u = __float_as_uint(f);
    u += 0x7fffu + ((u >> 16) & 1u);
    return (u16)(u >> 16);
}
DEV float bf2f(u16 h) { return __uint_as_float(((unsigned)h) << 16); }

DEV short8 ld16(const u16* p) { return *reinterpret_cast<const short8*>(p); }

DEV float gelu_f(float x) {                   // tanh-approx gelu, exp2-based
    const float u = x * (0.7978845608f + 0.0356774081f * x * x);
    const float e = __builtin_amdgcn_exp2f(u * 2.885390082f);   // e^(2u)
    const float t = 1.f - 2.f * __builtin_amdgcn_rcpf(e + 1.f); // tanh(u)
    return 0.5f * x * (1.f + t);
}

DEV unsigned pk2(float a, float b) {          // packed bf16x2 via HW cvt (RNE)
    unsigned r;
    asm("v_cvt_pk_bf16_f32 %0, %1, %2" : "=v"(r) : "v"(a), "v"(b));
    return r;
}

// async global->LDS, 16B per lane, LDS dest = wave-uniform base + lane*16
#define GLL16(gp, lp)                                                          \
    __builtin_amdgcn_global_load_lds(                                          \
        (const __attribute__((address_space(1))) void*)(gp),                   \
        (__attribute__((address_space(3))) void*)(lp), 16, 0, 0)

#define VMC(n) asm volatile("s_waitcnt vmcnt(" #n ")" ::: "memory")
#define LGKM0() asm volatile("s_waitcnt lgkmcnt(0)" ::: "memory")

// ---------------------------------------------------------------------------
// fp32 -> bf16 convert, all four weights in one grid-stride dispatch
// ---------------------------------------------------------------------------
__global__ __launch_bounds__(256) void cvt_all(
    const float* __restrict__ s0, const float* __restrict__ s1,
    const float* __restrict__ s2, const float* __restrict__ s3,
    u16* __restrict__ d0, u16* __restrict__ d1,
    u16* __restrict__ d2, u16* __restrict__ d3) {
    for (long i = (long)blockIdx.x * 256 + threadIdx.x; i < 3145728;
         i += (long)gridDim.x * 256) {
        const float* s; u16* d; long j = i;
        if (j < 786432)       { s = s0; d = d0; }
        else if (j < 1048576) { s = s1; d = d1; j -= 786432; }
        else if (j < 2097152) { s = s2; d = d2; j -= 1048576; }
        else                  { s = s3; d = d3; j -= 2097152; }
        float4 v = reinterpret_cast<const float4*>(s)[j];
        u16x4 o;
        o.x = f2bf(v.x); o.y = f2bf(v.y); o.z = f2bf(v.z); o.w = f2bf(v.w);
        reinterpret_cast<u16x4*>(d)[j] = o;
    }
}

// ---------------------------------------------------------------------------
// LayerNorm (fp32 in) -> bf16 out.  One block per row, 256 threads x 4 floats.
// ---------------------------------------------------------------------------
__global__ __launch_bounds__(256) void ln_bf16(const float* __restrict__ x,
                                               const float* __restrict__ gm,
                                               const float* __restrict__ bt,
                                               u16* __restrict__ out) {
    const int row = blockIdx.x, tid = threadIdx.x;
    const float4 v = reinterpret_cast<const float4*>(x + (long)row * 1024)[tid];
    float s  = v.x + v.y + v.z + v.w;
    float sq = v.x * v.x + v.y * v.y + v.z * v.z + v.w * v.w;
#pragma unroll
    for (int off = 1; off <= 32; off <<= 1) {
        s  += __shfl_xor(s, off);
        sq += __shfl_xor(sq, off);
    }
    __shared__ float ss[4], ssq[4];
    const int wave = tid >> 6, lane = tid & 63;
    if (lane == 0) { ss[wave] = s; ssq[wave] = sq; }
    __syncthreads();
    s  = ss[0] + ss[1] + ss[2] + ss[3];
    sq = ssq[0] + ssq[1] + ssq[2] + ssq[3];
    const float mu   = s * (1.f / 1024.f);
    const float var  = sq * (1.f / 1024.f) - mu * mu;
    const float rstd = rsqrtf(var + 1e-5f);
    const float4 g4 = reinterpret_cast<const float4*>(gm)[tid];
    const float4 b4 = reinterpret_cast<const float4*>(bt)[tid];
    u16x4 o;
    o.x = f2bf((v.x - mu) * rstd * g4.x + b4.x);
    o.y = f2bf((v.y - mu) * rstd * g4.y + b4.y);
    o.z = f2bf((v.z - mu) * rstd * g4.z + b4.z);
    o.w = f2bf((v.w - mu) * rstd * g4.w + b4.w);
    reinterpret_cast<u16x4*>(out + (long)row * 1024)[tid] = o;
}

// ---------------------------------------------------------------------------
// GEMM, templated BK.
//   BK=32: two-barrier depth-2 pipeline, 32 KB LDS, 4+ blocks/CU
//          (R13/R17-measured best: FC1 ~101 us, VGPR 60).
//   BK=64: two-barrier depth-2, 64 KB LDS, 2 blocks/CU -- for grid-capped
//          dispatches (halves iteration count).
// 8x8 SUPERTILE block mapping (64 blocks/XCD working set; smcol-fastest).
// C[M,N] = A[M,K] @ B[N,K]^T + bias.  128x128 tile, 4 waves (2x2).
// XOR-swizzled LDS staging (pre-swizzled source + swizzled ds_read).
// MFMA (bfr, af) order -> row-major D frag.
// EPI: 1 = bf16 gelu out (direct u16x4), 2 = fp32 out + residual,
//      3 = QKV (Q pre-scaled; Q/K LDS-restaged full-line; V transposed).
// ---------------------------------------------------------------------------
#define TS(c, r) ((c) * 128 + (((((r) >> 3) ^ ((c) & 15))) << 3) + ((r) & 7))
#define CS(r, ck) ((r) * 128 + ((((ck) ^ ((r) & 15))) << 3))

template <int EPI, int BK>
__global__ __launch_bounds__(256, (BK == 32) ? 4 : 2) void gemm_bt(
    const u16* __restrict__ A, const u16* __restrict__ B,
    const float* __restrict__ bias, const float* res, float* outf,
    u16* __restrict__ outb, u16* __restrict__ Qb, u16* __restrict__ Kb,
    u16* __restrict__ Vtb, int M, int N, int K, int ldk) {
    constexpr int BUFU = (BK == 32) ? 8192 : 16384;   // u16 per buffer
    __shared__ u16 shpool[2 * BUFU];

    const int tid = threadIdx.x;
    const int wave = tid >> 6, lane = tid & 63;
    const int lo = lane & 15, g = lane >> 4;
    const int wr = wave >> 1, wc = wave & 1;

    // XCD-chunked wgid; 8x8 supertile decode (chunk = whole supertiles)
    const int nwg = gridDim.x, chunk = nwg >> 3;
    const int wgid = (blockIdx.x & 7) * chunk + (blockIdx.x >> 3);
    const int nSmCol = N >> 10;                  // (N/128)/8 supertile cols
    const int s = wgid >> 6, w6 = wgid & 63;
    const int bm = (s / nSmCol) * 8 + (w6 >> 3);
    const int bn = (s % nSmCol) * 8 + (w6 & 7);
    const int row0 = bm * 128, col0 = bn * 128;

    // staging source (pre-swizzled logical chunk so linear LDS dest = swizzled)
    const u16 *Ag, *Bg;
    if constexpr (BK == 32) {
        const int lrow = lane >> 2;
        const int lg   = (lane & 3) ^ ((lane >> 3) & 3);
        Ag = A + (long)(row0 + wave * 16 + lrow) * ldk + lg * 8;
        Bg = B + (long)(col0 + wave * 16 + lrow) * ldk + lg * 8;
    } else {
        const int lg = (lane & 7) ^ ((lane >> 3) & 7);
        Ag = A + (long)(row0 + wave * 32 + (lane >> 3)) * ldk + lg * 8;
        Bg = B + (long)(col0 + wave * 32 + (lane >> 3)) * ldk + lg * 8;
    }

    auto STAGE = [&](int tb, int kt) {
        if constexpr (BK == 32) {
            u16* Al = shpool + tb * 8192 + wave * 512;
            u16* Bl = Al + 4096;
            GLL16(Ag + (long)kt * 32, Al);
            GLL16(Ag + 64 * (long)ldk + (long)kt * 32, Al + 2048);
            GLL16(Bg + (long)kt * 32, Bl);
            GLL16(Bg + 64 * (long)ldk + (long)kt * 32, Bl + 2048);
        } else {
            u16* Al = shpool + tb * 16384 + wave * 2048;
            u16* Bl = Al + 8192;
            GLL16(Ag + (long)kt * 64,                  Al);
            GLL16(Ag + (long)kt * 64 +  8 * (long)ldk, Al + 512);
            GLL16(Ag + (long)kt * 64 + 16 * (long)ldk, Al + 1024);
            GLL16(Ag + (long)kt * 64 + 24 * (long)ldk, Al + 1536);
            GLL16(Bg + (long)kt * 64,                  Bl);
            GLL16(Bg + (long)kt * 64 +  8 * (long)ldk, Bl + 512);
            GLL16(Bg + (long)kt * 64 + 16 * (long)ldk, Bl + 1024);
            GLL16(Bg + (long)kt * 64 + 24 * (long)ldk, Bl + 1536);
        }
    };

    f32x4 acc[4][4] = {};

    STAGE(0, 0);
    STAGE(1, 1);

    const int T = K / BK;
    for (int t = 0; t < T; ++t) {
        const int cur = t & 1;
        if (t + 1 < T) {
            if constexpr (BK == 32) { VMC(4); } else { VMC(8); }
        } else { VMC(0); }
        __builtin_amdgcn_s_barrier();         // tile t visible to all waves
        const u16* As = shpool + cur * BUFU;
        const u16* Bs = As + BUFU / 2;
        if constexpr (BK == 32) {
            short8 af[4], bfr[4];
            const int agp = g ^ ((lo >> 1) & 3);
#pragma unroll
            for (int m = 0; m < 4; ++m)
                af[m] = ld16(&As[(wr * 64 + m * 16 + lo) * 32 + agp * 8]);
#pragma unroll
            for (int n = 0; n < 4; ++n)
                bfr[n] = ld16(&Bs[(wc * 64 + n * 16 + lo) * 32 + agp * 8]);
            LGKM0();                          // own reads drained (WAR fence)
            __builtin_amdgcn_s_barrier();     // all waves' reads done
            if (t + 2 < T) STAGE(cur, t + 2);
#pragma unroll
            for (int m = 0; m < 4; ++m)
#pragma unroll
                for (int n = 0; n < 4; ++n)
                    acc[m][n] = __builtin_amdgcn_mfma_f32_16x16x32_bf16(
                        bfr[n], af[m], acc[m][n], 0, 0, 0);
        } else {
            short8 af[2][4], bfr[2][4];
#pragma unroll
            for (int ks = 0; ks < 2; ++ks) {
                const int ch = ((ks * 4 + g) ^ (lo & 7)) * 8;
#pragma unroll
                for (int m = 0; m < 4; ++m)
                    af[ks][m] = ld16(&As[(wr * 64 + m * 16 + lo) * 64 + ch]);
#pragma unroll
                for (int n = 0; n < 4; ++n)
                    bfr[ks][n] = ld16(&Bs[(wc * 64 + n * 16 + lo) * 64 + ch]);
            }
            LGKM0();
            __builtin_amdgcn_s_barrier();
            if (t + 2 < T) STAGE(cur, t + 2);
#pragma unroll
            for (int ks = 0; ks < 2; ++ks)
#pragma unroll
                for (int m = 0; m < 4; ++m)
#pragma unroll
                    for (int n = 0; n < 4; ++n)
                        acc[m][n] = __builtin_amdgcn_mfma_f32_16x16x32_bf16(
                            bfr[ks][n], af[ks][m], acc[m][n], 0, 0, 0);
        }
    }

    // ---- EPI 1: gelu bf16, direct u16x4 stores (R13-verified fastest) ----
    if constexpr (EPI == 1) {
#pragma unroll
        for (int n = 0; n < 4; ++n) {
            const int cb = col0 + wc * 64 + n * 16 + g * 4;
            const float4 b4 = *reinterpret_cast<const float4*>(&bias[cb]);
#pragma unroll
            for (int m = 0; m < 4; ++m) {
                const int r = row0 + wr * 64 + m * 16 + lo;
                u16x4 o = {f2bf(gelu_f(acc[m][n][0] + b4.x)),
                           f2bf(gelu_f(acc[m][n][1] + b4.y)),
                           f2bf(gelu_f(acc[m][n][2] + b4.z)),
                           f2bf(gelu_f(acc[m][n][3] + b4.w))};
                *reinterpret_cast<u16x4*>(&outb[(long)r * N + cb]) = o;
            }
        }
        return;
    }

    // ---- EPI 3: QKV scatter (LDS reuse -> sync first) ----
    if constexpr (EPI == 3) {
        __syncthreads();          // all waves out of the K-loop (LDS reuse)
        const int part = col0 >> 10;          // 0=Q 1=K 2=V
        if (part == 2) {                      // V: transpose via LDS -> Vt
#pragma unroll
            for (int n = 0; n < 4; ++n) {
                const int cb = wc * 64 + n * 16 + g * 4;
                const float4 b4 = *reinterpret_cast<const float4*>(&bias[col0 + cb]);
#pragma unroll
                for (int m = 0; m < 4; ++m) {
                    const int rl = wr * 64 + m * 16 + lo;
                    shpool[TS(cb + 0, rl)] = f2bf(acc[m][n][0] + b4.x);
                    shpool[TS(cb + 1, rl)] = f2bf(acc[m][n][1] + b4.y);
                    shpool[TS(cb + 2, rl)] = f2bf(acc[m][n][2] + b4.z);
                    shpool[TS(cb + 3, rl)] = f2bf(acc[m][n][3] + b4.w);
                }
            }
            __syncthreads();
            const int c = tid >> 1, hlf = tid & 1;
            const int dcol = (col0 - 2048) + c;
            const int head = dcol >> 6, d = dcol & 63;
            const int bb = row0 >> 11;
            u16* dst = Vtb + ((long)(bb * 16 + head) * 64 + d) * 2048 +
                       (row0 & 2047) + hlf * 64;
            const u16* srcb = shpool + c * 128;
#pragma unroll
            for (int i = 0; i < 8; ++i) {
                const int pc = (hlf * 8 + i) ^ (c & 15);
                *reinterpret_cast<short8*>(dst + i * 8) =
                    *reinterpret_cast<const short8*>(srcb + pc * 8);
            }
            return;
        }
        // Q/K: LDS-restage -> one full 128B [BH,S,64] line per thread
        const float qs = (part == 0) ? 0.18033688f : 1.0f;  // Q in log2 domain
#pragma unroll
        for (int n = 0; n < 4; ++n) {
            const int cb = col0 + wc * 64 + n * 16 + g * 4;
            const float4 b4 = *reinterpret_cast<const float4*>(&bias[cb]);
            const int ch = wc * 8 + n * 2 + (g >> 1);
#pragma unroll
            for (int m = 0; m < 4; ++m) {
                const int r = wr * 64 + m * 16 + lo;
                u16x4 o = {f2bf((acc[m][n][0] + b4.x) * qs),
                           f2bf((acc[m][n][1] + b4.y) * qs),
                           f2bf((acc[m][n][2] + b4.z) * qs),
                           f2bf((acc[m][n][3] + b4.w) * qs)};
                *reinterpret_cast<u16x4*>(&shpool[CS(r, ch) + (g & 1) * 4]) = o;
            }
        }
        __syncthreads();
        const int row = tid >> 1, hl = tid & 1;
        const int headbase = (col0 & 1023) >> 6;
        const int head = headbase + hl;
        const int bb = row0 >> 11;
        const int srow = (row0 & 2047) + row;
        u16* drow = (part == 0 ? Qb : Kb) +
                    ((long)(bb * 16 + head) * 2048 + srow) * 64;
        const int rk = row & 15;
#pragma unroll
        for (int i = 0; i < 8; ++i) {
            const int ck = hl * 8 + i;
            *reinterpret_cast<short8*>(drow + i * 8) =
                *reinterpret_cast<const short8*>(&shpool[row * 128 + ((ck ^ rk) << 3)]);
        }
        return;
    }

    // ---- EPI 2: fp32 out + residual (direct) ----
#pragma unroll
    for (int n = 0; n < 4; ++n) {
        const int cb = col0 + wc * 64 + n * 16 + g * 4;
        const float4 b4 = *reinterpret_cast<const float4*>(&bias[cb]);
#pragma unroll
        for (int m = 0; m < 4; ++m) {
            const int r = row0 + wr * 64 + m * 16 + lo;
            const float4 rr = *reinterpret_cast<const float4*>(&res[(long)r * N + cb]);
            float4 o = {rr.x + acc[m][n][0] + b4.x, rr.y + acc[m][n][1] + b4.y,
                        rr.z + acc[m][n][2] + b4.z, rr.w + acc[m][n][3] + b4.w};
            *reinterpret_cast<float4*>(&outf[(long)r * N + cb]) = o;
        }
    }
}

// ---------------------------------------------------------------------------
// Causal flash attention, 32x32x16 MFMA, LDS-staged K/V (counted-vmcnt
// double-buffer).  Block = 4 waves = one (bh, 128-row q-strip).
// ---------------------------------------------------------------------------
__global__ __launch_bounds__(256) void attn_fwd32(
    const u16* __restrict__ Q, const u16* __restrict__ K,
    const u16* __restrict__ Vt, u16* __restrict__ O) {
    __shared__ u16 kvl[2][8192];   // per buf: K tile 4096 u16, V tile 4096 u16
    const int bh = blockIdx.x;
    const int strip = 15 - blockIdx.y;       // heavy strips dispatch first
    const int wave = threadIdx.x >> 6, lane = threadIdx.x & 63;
    const int lq = lane & 31, hi = lane >> 5;
    const int qw = strip * 128 + wave * 32;

    const u16* Kg = K + (long)bh * 2048 * 64;
    const u16* Vg = Vt + (long)bh * 64 * 2048;
    const int bb = bh >> 4, h = bh & 15;
    const u16* Qp = Q + ((long)bh * 2048 + qw) * 64;

    const int srow = wave * 8 + (lane >> 3);         // 0..31
    const int sc   = (lane & 7) ^ (srow & 7);        // logical 16B chunk

#define ASTAGE(b, kt) do {                                                     \
        const long kvb = (long)(kt) * 64;                                      \
        GLL16(Kg + (kvb + srow) * 64 + sc * 8,        &kvl[b][wave * 512]);    \
        GLL16(Kg + (kvb + 32 + srow) * 64 + sc * 8,   &kvl[b][2048 + wave * 512]); \
        GLL16(Vg + (long)srow * 2048 + kvb + sc * 8,  &kvl[b][4096 + wave * 512]); \
        GLL16(Vg + (long)(32 + srow) * 2048 + kvb + sc * 8,                    \
              &kvl[b][6144 + wave * 512]);                                     \
    } while (0)

    short8 qf[4];
#pragma unroll
    for (int ks = 0; ks < 4; ++ks)
        qf[ks] = ld16(Qp + lq * 64 + ks * 16 + hi * 8);

    f32x16 o0 = {}, o1 = {};
    float m = -1e30f, l = 0.f;
    const int q_abs = qw + lq;
    const int my_end = qw + 32;              // wave's causal kv end
    const int T = 2 * (strip + 1);           // block kv tiles (>= 2)
    const int swp = lq & 7;                  // read-side swizzle key

    ASTAGE(0, 0);
    ASTAGE(1, 1);

    for (int t = 0; t < T; ++t) {
        const int cur = t & 1;
        const int kv0 = t * 64;
        if (t + 1 < T) { VMC(4); } else { VMC(0); }
        __builtin_amdgcn_s_barrier();        // tile t landed for all waves
        const bool active = (kv0 < my_end);  // wave-uniform
        f32x16 s0 = {}, s1 = {};
        short8 vf0[4], vf1[4];
        if (active) {
            const u16* Kb = &kvl[cur][0];
            __builtin_amdgcn_s_setprio(1);
#pragma unroll
            for (int ks = 0; ks < 4; ++ks)
                s0 = __builtin_amdgcn_mfma_f32_32x32x16_bf16(
                    ld16(Kb + lq * 64 + ((ks * 2 + hi) ^ swp) * 8), qf[ks], s0, 0, 0, 0);
#pragma unroll
            for (int ks = 0; ks < 4; ++ks)
                s1 = __builtin_amdgcn_mfma_f32_32x32x16_bf16(
                    ld16(Kb + 2048 + lq * 64 + ((ks * 2 + hi) ^ swp) * 8), qf[ks], s1, 0, 0, 0);
            __builtin_amdgcn_s_setprio(0);
            const u16* Vb = &kvl[cur][4096];
#pragma unroll
            for (int c = 0; c < 4; ++c) {
                vf0[c] = ld16(Vb + lq * 64 + ((c * 2 + hi) ^ swp) * 8);
                vf1[c] = ld16(Vb + 2048 + lq * 64 + ((c * 2 + hi) ^ swp) * 8);
            }
        }
        LGKM0();                             // own LDS reads drained (WAR)
        __builtin_amdgcn_s_barrier();        // all waves' reads done
        if (t + 2 < T) ASTAGE(cur, t + 2);   // overwrite safe; flies under compute
        if (active) {
            float mt = -1e30f;
            if (kv0 + 64 >= my_end) {
#pragma unroll
                for (int r = 0; r < 16; ++r) {
                    const int kv = kv0 + (r & 3) + 8 * (r >> 2) + 4 * hi;
                    if (kv > q_abs) s0[r] = -1e30f;
                    mt = fmaxf(mt, s0[r]);
                    if (kv + 32 > q_abs) s1[r] = -1e30f;
                    mt = fmaxf(mt, s1[r]);
                }
            } else {
#pragma unroll
                for (int r = 0; r < 16; ++r)
                    mt = fmaxf(mt, fmaxf(s0[r], s1[r]));
            }
            mt = fmaxf(mt, __shfl_xor(mt, 32));

            if (!__all(mt <= m + 11.5f)) {
                const float mn = fmaxf(m, mt);
                const float corr = __builtin_amdgcn_exp2f(m - mn);
                m = mn;
                l *= corr;
                o0 *= corr; o1 *= corr;
            }
            float ps = 0.f;
#pragma unroll
            for (int r = 0; r < 16; ++r) {
                s0[r] = __builtin_amdgcn_exp2f(s0[r] - m); ps += s0[r];
                s1[r] = __builtin_amdgcn_exp2f(s1[r] - m); ps += s1[r];
            }
            l += ps;

            short8 pf[4];
#pragma unroll
            for (int c = 0; c < 4; ++c) {
                const f32x16& src = (c >> 1) ? s1 : s0;
                const int b = (c & 1) * 8;
                const unsigned A0 = pk2(src[b + 0], src[b + 1]);
                const unsigned A1 = pk2(src[b + 2], src[b + 3]);
                const unsigned B0 = pk2(src[b + 4], src[b + 5]);
                const unsigned B1 = pk2(src[b + 6], src[b + 7]);
                const unsigned S0 = hi ? A0 : B0;
                const unsigned S1 = hi ? A1 : B1;
                const unsigned R0 = (unsigned)__shfl_xor((int)S0, 32);
                const unsigned R1 = (unsigned)__shfl_xor((int)S1, 32);
                union { unsigned u[4]; short8 v; } fr;
                fr.u[0] = hi ? R0 : A0;
                fr.u[1] = hi ? R1 : A1;
                fr.u[2] = hi ? B0 : R0;
                fr.u[3] = hi ? B1 : R1;
                pf[c] = fr.v;
            }

            __builtin_amdgcn_s_setprio(1);
#pragma unroll
            for (int c = 0; c < 4; ++c) {
                o0 = __builtin_amdgcn_mfma_f32_32x32x16_bf16(
                    vf0[c], pf[c], o0, 0, 0, 0);
                o1 = __builtin_amdgcn_mfma_f32_32x32x16_bf16(
                    vf1[c], pf[c], o1, 0, 0, 0);
            }
            __builtin_amdgcn_s_setprio(0);
        }
    }
#undef ASTAGE

    l += __shfl_xor(l, 32);
    const float inv = 1.f / l;
    u16* Orow = O + ((long)(bb * 2048 + qw + lq)) * 1024 + h * 64;
#pragma unroll
    for (int k4 = 0; k4 < 4; ++k4) {
        u16x4 w0, w1;
#pragma unroll
        for (int j = 0; j < 4; ++j) {
            w0[j] = f2bf(o0[k4 * 4 + j] * inv);
            w1[j] = f2bf(o1[k4 * 4 + j] * inv);
        }
        *reinterpret_cast<u16x4*>(Orow + 8 * k4 + 4 * hi)      = w0;
        *reinterpret_cast<u16x4*>(Orow + 32 + 8 * k4 + 4 * hi) = w1;
    }
}

// ---------------------------------------------------------------------------
// launch
// ---------------------------------------------------------------------------
extern "C" void kernel_launch(void* const* d_in, const int* in_sizes, int n_in,
                              void* d_out, int out_size, void* d_ws, size_t ws_size,
                              hipStream_t stream) {
    const float* x      = (const float*)d_in[0];
    const float* ln1_g  = (const float*)d_in[1];
    const float* ln1_b  = (const float*)d_in[2];
    const float* qkv_w  = (const float*)d_in[3];
    const float* qkv_b  = (const float*)d_in[4];
    const float* out_w  = (const float*)d_in[5];
    const float* out_b  = (const float*)d_in[6];
    const float* ln2_g  = (const float*)d_in[7];
    const float* ln2_b  = (const float*)d_in[8];
    const float* fc1_w  = (const float*)d_in[9];
    const float* fc1_b  = (const float*)d_in[10];
    const float* fc2_w  = (const float*)d_in[11];
    const float* fc2_b  = (const float*)d_in[12];
    float* out = (float*)d_out;

    const size_t MB = 1024ull * 1024ull;
    if (ws_size < 120 * MB) return;
    char* ws = (char*)d_ws;
    u16* wqkv = (u16*)(ws + 0);        // 6 MB
    u16* wout = (u16*)(ws + 6 * MB);   // 2 MB
    u16* wfc1 = (u16*)(ws + 8 * MB);   // 8 MB
    u16* wfc2 = (u16*)(ws + 16 * MB);  // 8 MB
    u16* hbuf = (u16*)(ws + 24 * MB);  // 16 MB  (LN output, bf16)
    u16* obuf = (u16*)(ws + 40 * MB);  // 16 MB  (attn output, bf16)
    u16* Qb   = (u16*)(ws + 56 * MB);  // 16 MB
    u16* Kb   = (u16*)(ws + 72 * MB);  // 16 MB
    u16* Vtb  = (u16*)(ws + 88 * MB);  // 16 MB
    u16* gbuf = (u16*)(ws + 56 * MB);  // 64 MB  (FFN hidden, reuses Q/K/Vt)

    cvt_all<<<dim3(2048), 256, 0, stream>>>(qkv_w, out_w, fc1_w, fc2_w,
                                            wqkv, wout, wfc1, wfc2);

    ln_bf16<<<8192, 256, 0, stream>>>(x, ln1_g, ln1_b, hbuf);
    // QKV: BK32 depth-2, 4 blocks/CU, 1536 blocks
    gemm_bt<3, 32><<<dim3(1536), 256, 0, stream>>>(hbuf, wqkv, qkv_b, nullptr,
                                                   nullptr, nullptr, Qb, Kb, Vtb,
                                                   8192, 3072, 1024, 1024);
    attn_fwd32<<<dim3(64, 16), 256, 0, stream>>>(Qb, Kb, Vtb, obuf);
    // out-proj: grid-capped (512 blocks) -> BK64
    gemm_bt<2, 64><<<dim3(512), 256, 0, stream>>>(obuf, wout, out_b, x, out,
                                                  nullptr, nullptr, nullptr, nullptr,
                                                  8192, 1024, 1024, 1024);
    ln_bf16<<<8192, 256, 0, stream>>>(out, ln2_g, ln2_b, hbuf);
    // FC1: BK32 depth-2, 4 blocks/CU, 2048 blocks
    gemm_bt<1, 32><<<dim3(2048), 256, 0, stream>>>(hbuf, wfc1, fc1_b, nullptr,
                                                   nullptr, gbuf, nullptr, nullptr,
                                                   nullptr, 8192, 4096, 1024, 1024);
    // FC2: grid-capped (512 blocks), K=4096 -> BK64
    gemm_bt<2, 64><<<dim3(512), 256, 0, stream>>>(gbuf, wfc2, fc2_b, out, out,
                                                  nullptr, nullptr, nullptr, nullptr,
                                                  8192, 1024, 4096, 4096);
}